// Round 12
// baseline (126.879 us; speedup 1.0000x reference)
//
#include <hip/hip_runtime.h>

#define NB 32
#define NN 256
#define DD 64
#define SROW 68          // LDS row stride (floats); 17-float4 stride, ~0 conflicts measured
#define TPAD 17          // transpose scratch row stride
#define FMAXV 3.402823466e+38f

// R18: single dispatch (R13 skeleton, best 117.5 = ~78us fixed + ~39.6us
// kernel). The 40us kernel was the per-k s_load drain: SMEM completes
// OUT-of-order -> compiler can only lgkmcnt(0)-full-drain per k-step
// (R14/R15 pinning couldn't change that; R16's VMEM detour = 150us).
// Fix: stage the 32KB weight matrix into LDS (Ws) and read the wave-uniform
// 16-float slices as ds_read_b128 BROADCASTS (same-address = conflict-free).
// DS completes IN-order -> compiler emits partial lgkmcnt(N) waits (m97-
// style) -> the conv loop actually pipelines. Per-CU per conv: VALU 16.4K
// cyc (6.8us), DS ~8.5K cyc (hidden under VALU). Ws staged We1 before
// layer-1 barrier, re-staged We2 in the post-conv1 reduction window.
// LDS: Hs 69.6KB + Ws 32KB + partials ~5KB = ~108KB (1 block/CU, 16 waves).

__device__ __forceinline__ void conv_full(
    const float* Hs, const float* Ws, int n, int d0,
    float ti[16], float tj[16])
{
#pragma unroll
    for (int j = 0; j < 16; ++j) { ti[j] = 0.f; tj[j] = 0.f; }
    const float* hrow = Hs + (size_t)n * SROW;
#pragma unroll 1
    for (int kc = 0; kc < 4; ++kc) {           // rolled: I$-sized
        float h[16];
#pragma unroll
        for (int q = 0; q < 4; ++q) {
            float4 hv = *(const float4*)(hrow + kc * 16 + 4 * q);
            h[4*q+0] = hv.x; h[4*q+1] = hv.y; h[4*q+2] = hv.z; h[4*q+3] = hv.w;
        }
#pragma unroll
        for (int q = 0; q < 16; ++q) asm volatile("" : "+v"(h[q]));  // pin
#pragma unroll
        for (int kk = 0; kk < 16; ++kk) {      // static h[] index
            const int k = kc * 16 + kk;
            const float hk = h[kk];
            const float* wi = Ws + k * DD + d0;          // ds_read_b128 broadcast
            const float* wj = Ws + (DD + k) * DD + d0;   // ds_read_b128 broadcast
#pragma unroll
            for (int q = 0; q < 4; ++q) {
                float4 a = *(const float4*)(wi + 4 * q);
                float4 c = *(const float4*)(wj + 4 * q);
                ti[4*q+0] = fmaf(hk, a.x, ti[4*q+0]);
                ti[4*q+1] = fmaf(hk, a.y, ti[4*q+1]);
                ti[4*q+2] = fmaf(hk, a.z, ti[4*q+2]);
                ti[4*q+3] = fmaf(hk, a.w, ti[4*q+3]);
                tj[4*q+0] = fmaf(hk, c.x, tj[4*q+0]);
                tj[4*q+1] = fmaf(hk, c.y, tj[4*q+1]);
                tj[4*q+2] = fmaf(hk, c.z, tj[4*q+2]);
                tj[4*q+3] = fmaf(hk, c.w, tj[4*q+3]);
            }
        }
    }
}

__global__ __launch_bounds__(1024, 4) void k_all(
    const float* __restrict__ x,
    const float* __restrict__ W1,  const float* __restrict__ b1,
    const float* __restrict__ g1,  const float* __restrict__ beta1,
    const float* __restrict__ We1, const float* __restrict__ be1,
    const float* __restrict__ ge1, const float* __restrict__ bte1,
    const float* __restrict__ We2, const float* __restrict__ be2,
    const float* __restrict__ ge2, const float* __restrict__ bte2,
    const float* __restrict__ Wg1, const float* __restrict__ bg1,
    const float* __restrict__ Wg2, const float* __restrict__ bg2,
    float* __restrict__ out)
{
    __shared__ __align__(16) float Hs[NN * SROW];   // 69,632 B; also transpose scratch
    __shared__ __align__(16) float Ws[2 * DD * DD]; // 32 KB staged weight matrix
    __shared__ __align__(16) float PTmax[4][DD], PTmin[4][DD];
    __shared__ __align__(16) float RM[DD], RMn[DD];
    __shared__ __align__(16) float PS[4][DD], PM[4][DD];
    __shared__ __align__(16) float xg[2 * DD];
    __shared__ __align__(16) float hid[DD];

    const int b   = blockIdx.x;
    const int t   = threadIdx.x;
    const int l   = t & 63;                                 // node lane
    const int w   = __builtin_amdgcn_readfirstlane(t >> 6); // wave 0..15
    const int ng  = w >> 2;           // node-group 0..3
    const int d0  = (w & 3) * 16;     // wave-uniform dim slice
    const int n   = ng * 64 + l;      // this thread's node
    const int jd  = l >> 2;           // transpose-read: my dim index (0..15)
    const int cq  = l & 3;            // transpose-read: my node-chunk (0..3)
    float* Ts     = Hs + w * (64 * TPAD);   // per-wave 64x17 scratch

    // ======= stage Ws <= We1 (coalesced; 8 floats/thread) =======
    *(float4*)(Ws + t * 4)        = *(const float4*)(We1 + t * 4);
    *(float4*)(Ws + 4096 + t * 4) = *(const float4*)(We1 + 4096 + t * 4);

    // ================= P0: layer 1 -> Hs rows =================
    {
        float4 xv = *(const float4*)(x + ((size_t)b * NN + n) * 4);
#pragma unroll
        for (int q = 0; q < 4; ++q) {
            float hq[4];
#pragma unroll
            for (int u = 0; u < 4; ++u) {
                const int d = d0 + 4 * q + u;
                float a = b1[d];
                a = fmaf(xv.x, W1[0 * DD + d], a);
                a = fmaf(xv.y, W1[1 * DD + d], a);
                a = fmaf(xv.z, W1[2 * DD + d], a);
                a = fmaf(xv.w, W1[3 * DD + d], a);
                hq[u] = g1[d] * fmaxf(a, 0.f) + beta1[d];
            }
            *(float4*)(Hs + (size_t)n * SROW + d0 + 4 * q) =
                make_float4(hq[0], hq[1], hq[2], hq[3]);
        }
    }
    __syncthreads();   // Hs + Ws(We1) ready

    float ti[16], tj[16];

    // ================= conv1 =================
    conv_full(Hs, Ws, n, d0, ti, tj);
    __syncthreads();                       // conv1 reads of Hs + Ws done

    // tj -> transpose scratch; restage Ws <= We2 in the same window
#pragma unroll
    for (int j = 0; j < 16; ++j) Ts[l * TPAD + j] = tj[j];
    *(float4*)(Ws + t * 4)        = *(const float4*)(We2 + t * 4);
    *(float4*)(Ws + 4096 + t * 4) = *(const float4*)(We2 + 4096 + t * 4);
    __syncthreads();

    // column reduce: 16 in-lane + 4 shuffles
    {
        float mx = -FMAXV, mn = FMAXV;
#pragma unroll
        for (int r = 0; r < 16; ++r) {
            float v = Ts[(cq * 16 + r) * TPAD + jd];
            mx = fmaxf(mx, v); mn = fminf(mn, v);
        }
        mx = fmaxf(mx, __shfl_xor(mx, 1, 64));
        mx = fmaxf(mx, __shfl_xor(mx, 2, 64));
        mn = fminf(mn, __shfl_xor(mn, 1, 64));
        mn = fminf(mn, __shfl_xor(mn, 2, 64));
        if (cq == 0) { PTmax[ng][d0 + jd] = mx; PTmin[ng][d0 + jd] = mn; }
    }
    __syncthreads();

    // combine 4 node-groups
    {
        if (t < DD)
            RM[t] = fmaxf(fmaxf(PTmax[0][t], PTmax[1][t]),
                          fmaxf(PTmax[2][t], PTmax[3][t]));
        else if (t < 2 * DD) {
            const int d = t - DD;
            RMn[d] = fminf(fminf(PTmin[0][d], PTmin[1][d]),
                           fminf(PTmin[2][d], PTmin[3][d]));
        }
    }
    __syncthreads();

    // conv1 epilogue -> Hs rows (monotone bn o max)
    {
#pragma unroll
        for (int q = 0; q < 4; ++q) {
            float4 rmx = *(const float4*)(&RM[d0 + 4 * q]);    // broadcast
            float4 rmn = *(const float4*)(&RMn[d0 + 4 * q]);   // broadcast
            const float rmax[4] = {rmx.x, rmx.y, rmx.z, rmx.w};
            const float rmin[4] = {rmn.x, rmn.y, rmn.z, rmn.w};
            float hq[4];
#pragma unroll
            for (int u = 0; u < 4; ++u) {
                const int d = d0 + 4 * q + u;
                const float gv = ge1[d];
                const float sv = ti[4*q+u] + (gv >= 0.f ? rmax[u] : rmin[u]) + be1[d];
                hq[u] = gv * fmaxf(sv, 0.f) + bte1[d];
            }
            *(float4*)(Hs + (size_t)n * SROW + d0 + 4 * q) =
                make_float4(hq[0], hq[1], hq[2], hq[3]);
        }
    }
    __syncthreads();   // Hs(h2) + Ws(We2) ready

    // ================= conv2 =================
    conv_full(Hs, Ws, n, d0, ti, tj);
    __syncthreads();

#pragma unroll
    for (int j = 0; j < 16; ++j) Ts[l * TPAD + j] = tj[j];
    __syncthreads();

    {
        float mx = -FMAXV, mn = FMAXV;
#pragma unroll
        for (int r = 0; r < 16; ++r) {
            float v = Ts[(cq * 16 + r) * TPAD + jd];
            mx = fmaxf(mx, v); mn = fminf(mn, v);
        }
        mx = fmaxf(mx, __shfl_xor(mx, 1, 64));
        mx = fmaxf(mx, __shfl_xor(mx, 2, 64));
        mn = fminf(mn, __shfl_xor(mn, 1, 64));
        mn = fminf(mn, __shfl_xor(mn, 2, 64));
        if (cq == 0) { PTmax[ng][d0 + jd] = mx; PTmin[ng][d0 + jd] = mn; }
    }
    __syncthreads();

    {
        if (t < DD)
            RM[t] = fmaxf(fmaxf(PTmax[0][t], PTmax[1][t]),
                          fmaxf(PTmax[2][t], PTmax[3][t]));
        else if (t < 2 * DD) {
            const int d = t - DD;
            RMn[d] = fminf(fminf(PTmin[0][d], PTmin[1][d]),
                           fminf(PTmin[2][d], PTmin[3][d]));
        }
    }
    __syncthreads();

    // conv2 epilogue -> h3, into transpose scratch for pooling
    {
#pragma unroll
        for (int q = 0; q < 4; ++q) {
            float4 rmx4 = *(const float4*)(&RM[d0 + 4 * q]);
            float4 rmn4 = *(const float4*)(&RMn[d0 + 4 * q]);
            const float rmax[4] = {rmx4.x, rmx4.y, rmx4.z, rmx4.w};
            const float rmin[4] = {rmn4.x, rmn4.y, rmn4.z, rmn4.w};
#pragma unroll
            for (int u = 0; u < 4; ++u) {
                const int d = d0 + 4 * q + u;
                const float gv = ge2[d];
                const float sv = ti[4*q+u] + (gv >= 0.f ? rmax[u] : rmin[u]) + be2[d];
                Ts[l * TPAD + 4 * q + u] = gv * fmaxf(sv, 0.f) + bte2[d];
            }
        }
    }
    __syncthreads();

    // pooling: column reduce sum & max
    {
        float s = 0.f, mx = -FMAXV;
#pragma unroll
        for (int r = 0; r < 16; ++r) {
            float v = Ts[(cq * 16 + r) * TPAD + jd];
            s += v; mx = fmaxf(mx, v);
        }
        s += __shfl_xor(s, 1, 64);
        s += __shfl_xor(s, 2, 64);
        mx = fmaxf(mx, __shfl_xor(mx, 1, 64));
        mx = fmaxf(mx, __shfl_xor(mx, 2, 64));
        if (cq == 0) { PS[ng][d0 + jd] = s; PM[ng][d0 + jd] = mx; }
    }
    __syncthreads();

    // pooling finalize + head MLP
    if (t < DD) {
        xg[t] = (PS[0][t] + PS[1][t] + PS[2][t] + PS[3][t]) * (1.f / 256.f);
    } else if (t < 2 * DD) {
        const int d = t - DD;
        xg[t] = fmaxf(fmaxf(PM[0][d], PM[1][d]), fmaxf(PM[2][d], PM[3][d]));
    }
    __syncthreads();
    if (t < DD) {
        float a = bg1[t];
#pragma unroll
        for (int k = 0; k < 2 * DD; ++k) a = fmaf(xg[k], Wg1[k * DD + t], a);
        hid[t] = fmaxf(a, 0.f);
    }
    __syncthreads();
    if (t < 2) {
        float o = bg2[t];
#pragma unroll
        for (int j = 0; j < DD; ++j) o = fmaf(hid[j], Wg2[j * 2 + t], o);
        out[b * 2 + t] = o;
    }
}

extern "C" void kernel_launch(void* const* d_in, const int* in_sizes, int n_in,
                              void* d_out, int out_size, void* d_ws, size_t ws_size,
                              hipStream_t stream) {
    const float* x     = (const float*)d_in[0];
    const float* W1    = (const float*)d_in[1];
    const float* b1    = (const float*)d_in[2];
    const float* g1    = (const float*)d_in[3];
    const float* beta1 = (const float*)d_in[4];
    const float* We1   = (const float*)d_in[5];
    const float* be1   = (const float*)d_in[6];
    const float* ge1   = (const float*)d_in[7];
    const float* bte1  = (const float*)d_in[8];
    const float* We2   = (const float*)d_in[9];
    const float* be2   = (const float*)d_in[10];
    const float* ge2   = (const float*)d_in[11];
    const float* bte2  = (const float*)d_in[12];
    const float* Wg1   = (const float*)d_in[13];
    const float* bg1   = (const float*)d_in[14];
    const float* Wg2   = (const float*)d_in[15];
    const float* bg2   = (const float*)d_in[16];

    k_all<<<dim3(NB), dim3(1024), 0, stream>>>(
        x, W1, b1, g1, beta1,
        We1, be1, ge1, bte1,
        We2, be2, ge2, bte2,
        Wg1, bg1, Wg2, bg2, (float*)d_out);
}

// Round 13
// 116.081 us; speedup vs baseline: 1.0930x; 1.0930x over previous
//
#include <hip/hip_runtime.h>

#define NB 32
#define NN 256
#define DD 64
#define FMAXV 3.402823466e+38f

// R19: single dispatch, 32 blocks x 1024. Diagnosis across R10-R18: the conv
// loop issues 1 weight load per 4 FMAs with no node-reuse; 8192 loads/CU/conv
// bound the kernel on either pipe (SMEM ~4cyc -> 13.7us/conv = R13's 39.6;
// DS b128 ~12cyc -> 41us = R18's 43.4). Fix = register tiling on nodes:
//   thread = 4 nodes x 8 outputs (acc[4][8]); waves 0-7 = ti dims, 8-15 =
//   tj dims (wave-specialized weight stream). h stored K-MAJOR (HT[k][256])
//   so per k: ONE ds_read_b128 (lane-consecutive, conflict-free, k in the
//   16-bit imm offset) + 2 uniform s_load_dwordx4 + 32 FMA.
// Per CU/conv: DS 1024x12=12K cyc, SMEM 2048x4=8K, VALU 16.4K -> VALU-bound
// (~7us/conv vs ~15 before). tj-reduce & pooling: in-register fold + 64-lane
// butterfly (lanes span all 256 nodes) -> no transpose scratch, fewer phases.
// LDS: HT 64KB + ~1KB. Ascending-k accumulation preserved.

__device__ __forceinline__ void conv_quad(
    const float* HT, int nq, int d0, const float* __restrict__ Wb,
    float acc[4][8])
{
#pragma unroll
    for (int r = 0; r < 4; ++r)
#pragma unroll
        for (int c = 0; c < 8; ++c) acc[r][c] = 0.f;
    const float* hp = HT + 4 * nq;
#pragma unroll 4
    for (int k = 0; k < DD; ++k) {
        float4 hv = *(const float4*)(hp + k * NN);            // 1 ds_read_b128
        float4 w0 = *(const float4*)(Wb + k * DD + d0);       // s_load_dwordx4
        float4 w1 = *(const float4*)(Wb + k * DD + d0 + 4);   // s_load_dwordx4
        const float hr[4] = {hv.x, hv.y, hv.z, hv.w};
        const float wv[8] = {w0.x, w0.y, w0.z, w0.w, w1.x, w1.y, w1.z, w1.w};
#pragma unroll
        for (int r = 0; r < 4; ++r)
#pragma unroll
            for (int c = 0; c < 8; ++c)
                acc[r][c] = fmaf(hr[r], wv[c], acc[r][c]);
    }
}

__global__ __launch_bounds__(1024, 4) void k_all(
    const float* __restrict__ x,
    const float* __restrict__ W1,  const float* __restrict__ b1,
    const float* __restrict__ g1,  const float* __restrict__ beta1,
    const float* __restrict__ We1, const float* __restrict__ be1,
    const float* __restrict__ ge1, const float* __restrict__ bte1,
    const float* __restrict__ We2, const float* __restrict__ be2,
    const float* __restrict__ ge2, const float* __restrict__ bte2,
    const float* __restrict__ Wg1, const float* __restrict__ bg1,
    const float* __restrict__ Wg2, const float* __restrict__ bg2,
    float* __restrict__ out)
{
    __shared__ __align__(16) float HT[DD * NN];   // 64 KB, k-major h
    __shared__ float RMx[DD], RMn[DD];
    __shared__ float xg[2 * DD], hid[DD];

    const int b  = blockIdx.x;
    const int t  = threadIdx.x;
    const int nq = t & 63;                                  // node-quad (lane)
    const int os = __builtin_amdgcn_readfirstlane(t >> 6);  // wave 0..15
    const bool isTi = (os < 8);
    const int d0 = (os & 7) * 8;                            // 8-dim out slice

    // ========== layer 1: dims 4*os..+3 for nodes 4nq..4nq+3 -> HT ==========
    {
        const int dl = os * 4;
        float hq[4][4];                                     // [u=dim][r=node]
#pragma unroll
        for (int r = 0; r < 4; ++r) {
            float4 xv = *(const float4*)(x + ((size_t)b * NN + 4 * nq + r) * 4);
#pragma unroll
            for (int u = 0; u < 4; ++u) {
                const int d = dl + u;
                float a = b1[d];
                a = fmaf(xv.x, W1[0 * DD + d], a);
                a = fmaf(xv.y, W1[1 * DD + d], a);
                a = fmaf(xv.z, W1[2 * DD + d], a);
                a = fmaf(xv.w, W1[3 * DD + d], a);
                hq[u][r] = g1[d] * fmaxf(a, 0.f) + beta1[d];
            }
        }
#pragma unroll
        for (int u = 0; u < 4; ++u)
            *(float4*)(HT + (dl + u) * NN + 4 * nq) =
                make_float4(hq[u][0], hq[u][1], hq[u][2], hq[u][3]);
    }
    __syncthreads();

    float acc[4][8];

    // ========== conv1 ==========
    conv_quad(HT, nq, d0, isTi ? We1 : (We1 + DD * DD), acc);
    if (!isTi) {   // tj waves: in-register max/min over all 256 nodes
        float mx[8], mn[8];
#pragma unroll
        for (int c = 0; c < 8; ++c) {
            mx[c] = fmaxf(fmaxf(acc[0][c], acc[1][c]), fmaxf(acc[2][c], acc[3][c]));
            mn[c] = fminf(fminf(acc[0][c], acc[1][c]), fminf(acc[2][c], acc[3][c]));
        }
#pragma unroll
        for (int m = 1; m < 64; m <<= 1) {
#pragma unroll
            for (int c = 0; c < 8; ++c) {
                mx[c] = fmaxf(mx[c], __shfl_xor(mx[c], m, 64));
                mn[c] = fminf(mn[c], __shfl_xor(mn[c], m, 64));
            }
        }
        float smx = mx[0], smn = mn[0];
#pragma unroll
        for (int c = 1; c < 8; ++c) {
            smx = (nq == c) ? mx[c] : smx;
            smn = (nq == c) ? mn[c] : smn;
        }
        if (nq < 8) { RMx[d0 + nq] = smx; RMn[d0 + nq] = smn; }
    }
    __syncthreads();   // RM ready; all conv1 HT reads complete

    // ========== conv1 epilogue (ti waves): h2 -> HT ==========
    if (isTi) {
#pragma unroll
        for (int c = 0; c < 8; ++c) {
            const int d = d0 + c;
            const float gv = ge1[d], bv = be1[d], bt = bte1[d];
            const float pick = (gv >= 0.f) ? RMx[d] : RMn[d];
            float4 o;
            o.x = gv * fmaxf(acc[0][c] + pick + bv, 0.f) + bt;
            o.y = gv * fmaxf(acc[1][c] + pick + bv, 0.f) + bt;
            o.z = gv * fmaxf(acc[2][c] + pick + bv, 0.f) + bt;
            o.w = gv * fmaxf(acc[3][c] + pick + bv, 0.f) + bt;
            *(float4*)(HT + d * NN + 4 * nq) = o;
        }
    }
    __syncthreads();   // h2 ready

    // ========== conv2 ==========
    conv_quad(HT, nq, d0, isTi ? We2 : (We2 + DD * DD), acc);
    if (!isTi) {
        float mx[8], mn[8];
#pragma unroll
        for (int c = 0; c < 8; ++c) {
            mx[c] = fmaxf(fmaxf(acc[0][c], acc[1][c]), fmaxf(acc[2][c], acc[3][c]));
            mn[c] = fminf(fminf(acc[0][c], acc[1][c]), fminf(acc[2][c], acc[3][c]));
        }
#pragma unroll
        for (int m = 1; m < 64; m <<= 1) {
#pragma unroll
            for (int c = 0; c < 8; ++c) {
                mx[c] = fmaxf(mx[c], __shfl_xor(mx[c], m, 64));
                mn[c] = fminf(mn[c], __shfl_xor(mn[c], m, 64));
            }
        }
        float smx = mx[0], smn = mn[0];
#pragma unroll
        for (int c = 1; c < 8; ++c) {
            smx = (nq == c) ? mx[c] : smx;
            smn = (nq == c) ? mn[c] : smn;
        }
        if (nq < 8) { RMx[d0 + nq] = smx; RMn[d0 + nq] = smn; }
    }
    __syncthreads();

    // ========== conv2 epilogue + pooling (ti waves) ==========
    if (isTi) {
        float sm[8], mxp[8];
#pragma unroll
        for (int c = 0; c < 8; ++c) {
            const int d = d0 + c;
            const float gv = ge2[d], bv = be2[d], bt = bte2[d];
            const float pick = (gv >= 0.f) ? RMx[d] : RMn[d];
            const float h0 = gv * fmaxf(acc[0][c] + pick + bv, 0.f) + bt;
            const float h1 = gv * fmaxf(acc[1][c] + pick + bv, 0.f) + bt;
            const float h2 = gv * fmaxf(acc[2][c] + pick + bv, 0.f) + bt;
            const float h3 = gv * fmaxf(acc[3][c] + pick + bv, 0.f) + bt;
            sm[c]  = (h0 + h1) + (h2 + h3);
            mxp[c] = fmaxf(fmaxf(h0, h1), fmaxf(h2, h3));
        }
#pragma unroll
        for (int m = 1; m < 64; m <<= 1) {
#pragma unroll
            for (int c = 0; c < 8; ++c) {
                sm[c]  += __shfl_xor(sm[c], m, 64);
                mxp[c]  = fmaxf(mxp[c], __shfl_xor(mxp[c], m, 64));
            }
        }
        float ssm = sm[0], smx = mxp[0];
#pragma unroll
        for (int c = 1; c < 8; ++c) {
            ssm = (nq == c) ? sm[c]  : ssm;
            smx = (nq == c) ? mxp[c] : smx;
        }
        if (nq < 8) {
            xg[d0 + nq]      = ssm * (1.f / 256.f);
            xg[DD + d0 + nq] = smx;
        }
    }
    __syncthreads();

    // ========== head MLP ==========
    if (t < DD) {
        float a = bg1[t];
#pragma unroll
        for (int k = 0; k < 2 * DD; ++k) a = fmaf(xg[k], Wg1[k * DD + t], a);
        hid[t] = fmaxf(a, 0.f);
    }
    __syncthreads();
    if (t < 2) {
        float o = bg2[t];
#pragma unroll
        for (int j = 0; j < DD; ++j) o = fmaf(hid[j], Wg2[j * 2 + t], o);
        out[b * 2 + t] = o;
    }
}

extern "C" void kernel_launch(void* const* d_in, const int* in_sizes, int n_in,
                              void* d_out, int out_size, void* d_ws, size_t ws_size,
                              hipStream_t stream) {
    const float* x     = (const float*)d_in[0];
    const float* W1    = (const float*)d_in[1];
    const float* b1    = (const float*)d_in[2];
    const float* g1    = (const float*)d_in[3];
    const float* beta1 = (const float*)d_in[4];
    const float* We1   = (const float*)d_in[5];
    const float* be1   = (const float*)d_in[6];
    const float* ge1   = (const float*)d_in[7];
    const float* bte1  = (const float*)d_in[8];
    const float* We2   = (const float*)d_in[9];
    const float* be2   = (const float*)d_in[10];
    const float* ge2   = (const float*)d_in[11];
    const float* bte2  = (const float*)d_in[12];
    const float* Wg1   = (const float*)d_in[13];
    const float* bg1   = (const float*)d_in[14];
    const float* Wg2   = (const float*)d_in[15];
    const float* bg2   = (const float*)d_in[16];

    k_all<<<dim3(NB), dim3(1024), 0, stream>>>(
        x, W1, b1, g1, beta1,
        We1, be1, ge1, bte1,
        We2, be2, ge2, bte2,
        Wg1, bg1, Wg2, bg2, (float*)d_out);
}